// Round 22
// baseline (63.653 us; speedup 1.0000x reference)
//
#include <hip/hip_runtime.h>
#include <hip/hip_fp16.h>
#include <math.h>

#define D_DIM 160
#define H_DIM 192
#define W_DIM 192
#define HWN   (H_DIM * W_DIM)                 // 36864
#define NTOT  ((size_t)D_DIM * H_DIM * W_DIM) // 5898240

#define C1 0.0001f   // 0.01^2
#define C2 0.0009f   // 0.03^2

#define HSEG 16                    // output rows per wave (waves > work: R20)
#define NHSEG (H_DIM / HSEG)       // 12
#define NWAVES (NHSEG * 3 * D_DIM) // 5760 (one wave per block)
#define MARCH (HSEG + 10)          // 26 input rows per wave

#define DC 40                      // pass2 d-outputs per block
#define DCHUNKS 4                  // 4*40 = 160 exactly

struct GaussW { float g[11]; };

struct alignas(8) H4 { __half2 ab; __half2 cd; };   // f0,f1 | f2,f3

__device__ __forceinline__ int clampi(int v, int lo, int hi) {
    return min(max(v, lo), hi);
}

// Pass 1: R21 verbatim except HSEG 24->16 (bit-identical decomposition;
// only the wave->row assignment changes). 1-wave blocks, emission-form
// H-blur, double-buffered LDS row, one fence/step, depth-4 prefetch.
template<int J>
__device__ __forceinline__ void p1_steps(
    const float* __restrict__ pa1, const float* __restrict__ pa2,
    const float* __restrict__ pb1, const float* __restrict__ pb2,
    H4* __restrict__ ep0123, __half* __restrict__ ep4,
    float2* __restrict__ sbuf0, float2* __restrict__ sbuf1,
    const int lane, const bool va, const bool vb,
    const int hbase, const GaussW& gw, float (&rows)[5][11],
    float2 wAv, float2 wAu, float2 wBv, float2 wBu,
    float2 wCv, float2 wCu)
{
    if constexpr (J < MARCH) {
        // issue prefetch for row J+4 (in flight across ~4 steps)
        float2 pfv = {0.f, 0.f}, pfu = {0.f, 0.f};
        if constexpr (J + 4 < MARCH) {
            const int hc = clampi(hbase - 5 + J + 4, 0, H_DIM - 1);
            const size_t ro = (size_t)hc * W_DIM;
            pfv.x = pa1[ro]; pfv.y = pa2[ro];
            pfu.x = pb1[ro]; pfu.y = pb2[ro];
        }

        __builtin_amdgcn_wave_barrier();    // one fence per step

        // stage row J+1 into the other buffer (masked to zero outside)
        if constexpr (J + 1 < MARCH) {
            const int h1 = hbase - 5 + (J + 1);
            const bool ok1 = (h1 >= 0) && (h1 < H_DIM);   // wave-uniform
            float2* wb = ((J + 1) & 1) ? sbuf1 : sbuf0;
            const float2 zz = {0.f, 0.f};
            wb[lane] = (ok1 && va) ? wAv : zz;
            if (lane < 10) wb[64 + lane] = (ok1 && vb) ? wAu : zz;
        }

        // read row J (staged last step; write->read spans a full step);
        // invalid rows record exact zeros (fma(g,0,s)==s bitwise).
        const int hin = hbase - 5 + J;
        float a0 = 0.f, a1 = 0.f, a2 = 0.f, a3 = 0.f, a4 = 0.f;
        if (hin >= 0 && hin < H_DIM) {      // wave-uniform
            const float2* rb = (J & 1) ? sbuf1 : sbuf0;
#pragma unroll
            for (int k = 0; k < 11; ++k) {
                float2 p = rb[lane + k];
                float t1 = gw.g[k] * p.x;
                float t2 = gw.g[k] * p.y;
                a0 += t1;
                a1 += t2;
                a2 = fmaf(t1, p.x, a2);
                a3 = fmaf(t2, p.y, a3);
                a4 = fmaf(t1, p.y, a4);
            }
        }
        rows[0][J % 11] = a0;
        rows[1][J % 11] = a1;
        rows[2][J % 11] = a2;
        rows[3][J % 11] = a3;
        rows[4][J % 11] = a4;

        // output row o = J-10 complete: emission dot-product over the ring
        if constexpr (J >= 10) {
            constexpr int o = J - 10;
            float s0 = 0.f, s1 = 0.f, s2 = 0.f, s3 = 0.f, s4 = 0.f;
#pragma unroll
            for (int k = 0; k < 11; ++k) {
                const float wgt = gw.g[k];
                const int slot = (o + k) % 11;  // constexpr after unroll
                s0 = fmaf(wgt, rows[0][slot], s0);
                s1 = fmaf(wgt, rows[1][slot], s1);
                s2 = fmaf(wgt, rows[2][slot], s2);
                s3 = fmaf(wgt, rows[3][slot], s3);
                s4 = fmaf(wgt, rows[4][slot], s4);
            }
            const size_t rb_ = (size_t)o * W_DIM;
            float2 v01; v01.x = s0; v01.y = s1;
            float2 v23; v23.x = s2; v23.y = s3;
            H4 q;
            q.ab = __float22half2_rn(v01);
            q.cd = __float22half2_rn(v23);
            ep0123[rb_] = q;
            ep4[rb_]    = __float2half_rn(s4);
        }

        p1_steps<J + 1>(pa1, pa2, pb1, pb2, ep0123, ep4, sbuf0, sbuf1,
                        lane, va, vb, hbase, gw, rows,
                        wBv, wBu, wCv, wCu, pfv, pfu);
    }
}

__global__ __launch_bounds__(64) void ssim_pass1(
    const float* __restrict__ img1, const float* __restrict__ img2,
    H4* __restrict__ f0123, __half* __restrict__ f4,
    double* __restrict__ accum, GaussW gw)
{
    // zero reduction cell for pass2 (stream-ordered visibility)
    if (blockIdx.x == 0 && threadIdx.x == 0) accum[0] = 0.0;

    __shared__ float2 sxy[2][80];

    const int lane = threadIdx.x;           // 64-thread block = one wave
    const int wid  = blockIdx.x;
    const int hseg = wid % NHSEG;
    const int t    = wid / NHSEG;
    const int wtile = t % 3;
    const int d     = t / 3;
    const int w0    = wtile * 64;
    const int hbase = hseg * HSEG;

    const int  cola = w0 - 5 + lane;                 // stage col 1
    const bool va   = (cola >= 0) && (cola < W_DIM);
    const int  colb = w0 + 59 + lane;                // stage col 2 (lane<10)
    const bool vb   = (lane < 10) && (colb < W_DIM);
    const int  colac = clampi(cola, 0, W_DIM - 1);   // clamped (masked lanes)
    const int  colbc = min(colb, W_DIM - 1);

    const size_t plane = (size_t)d * HWN;
    const float* pa1 = img1 + plane + colac;
    const float* pa2 = img2 + plane + colac;
    const float* pb1 = img1 + plane + colbc;
    const float* pb2 = img2 + plane + colbc;

    float rows[5][11];
#pragma unroll
    for (int f = 0; f < 5; ++f)
#pragma unroll
        for (int s = 0; s < 11; ++s) rows[f][s] = 0.f;

    float2* sbuf0 = sxy[0];
    float2* sbuf1 = sxy[1];

    // prologue: load rows 0..3; stage row 0 into buf[0]
    float2 r0v, r0u, r1v, r1u, r2v, r2u, r3v, r3u;
    {
        const int h0 = clampi(hbase - 5, 0, H_DIM - 1);
        const int h1 = clampi(hbase - 4, 0, H_DIM - 1);
        const int h2 = clampi(hbase - 3, 0, H_DIM - 1);
        const int h3 = clampi(hbase - 2, 0, H_DIM - 1);
        const size_t q0 = (size_t)h0 * W_DIM;
        const size_t q1 = (size_t)h1 * W_DIM;
        const size_t q2 = (size_t)h2 * W_DIM;
        const size_t q3 = (size_t)h3 * W_DIM;
        r0v.x = pa1[q0]; r0v.y = pa2[q0]; r0u.x = pb1[q0]; r0u.y = pb2[q0];
        r1v.x = pa1[q1]; r1v.y = pa2[q1]; r1u.x = pb1[q1]; r1u.y = pb2[q1];
        r2v.x = pa1[q2]; r2v.y = pa2[q2]; r2u.x = pb1[q2]; r2u.y = pb2[q2];
        r3v.x = pa1[q3]; r3v.y = pa2[q3]; r3u.x = pb1[q3]; r3u.y = pb2[q3];
    }
    {
        const bool ok0 = (hbase - 5 >= 0);           // wave-uniform
        const float2 zz = {0.f, 0.f};
        sbuf0[lane] = (ok0 && va) ? r0v : zz;
        if (lane < 10) sbuf0[64 + lane] = (ok0 && vb) ? r0u : zz;
    }

    const size_t ebase = plane + (size_t)hbase * W_DIM + (w0 + lane);
    H4*     ep0123 = f0123 + ebase;
    __half* ep4    = f4    + ebase;

    p1_steps<0>(pa1, pa2, pb1, pb2, ep0123, ep4, sbuf0, sbuf1,
                lane, va, vb, hbase, gw, rows,
                r1v, r1u, r2v, r2u, r3v, r3u);
}

// Pass 2: R14/R18/R19/R21 VERBATIM (fire-and-forget atomic; absmax 0.0).
__global__ __launch_bounds__(256) void ssim_pass2(
    const H4* __restrict__ f0123, const __half* __restrict__ f4,
    double* __restrict__ accum, GaussW gwts)
{
    const int hw = blockIdx.x * 256 + threadIdx.x;
    const int d0 = blockIdx.y * DC;

    float2 w01[11], w23[11];
    float  w4[11];

    // prologue: planes d0-5 .. d0+5 into slots 0..10 (33 independent loads)
#pragma unroll
    for (int i = 0; i < 11; ++i) {
        int p = d0 - 5 + i;
        bool ok = (p >= 0) && (p < D_DIM);
        size_t off = (size_t)(ok ? p : 0) * HWN + hw;
        float2 zz = {0.f, 0.f};
        H4 q = f0123[off];
        w01[i] = ok ? __half22float2(q.ab) : zz;
        w23[i] = ok ? __half22float2(q.cd) : zz;
        w4[i]  = ok ? __half2float(f4[off]) : 0.f;
    }

    // pending planes d0+6 (pA) and d0+7 (pB), raw fp16 registers
    H4 pA, pB; __half pA4, pB4; bool okA, okB;
    {
        int p = d0 + 6; okA = (p < D_DIM);
        size_t off = (size_t)(okA ? p : 0) * HWN + hw;
        pA = f0123[off]; pA4 = f4[off];
    }
    {
        int p = d0 + 7; okB = (p < D_DIM);
        size_t off = (size_t)(okB ? p : 0) * HWN + hw;
        pB = f0123[off]; pB4 = f4[off];
    }

    float ssum = 0.f;
#pragma unroll
    for (int j = 0; j < DC; ++j) {
        const int d = d0 + j;

        // consume window: planes d-5..d+5 at slots (j+k)%11
        if (d < D_DIM) {
            float m0 = 0.f, m1 = 0.f, m2 = 0.f, m3 = 0.f, m4 = 0.f;
#pragma unroll
            for (int k = 0; k < 11; ++k) {
                const float wk = gwts.g[k];
                const int s = (j + k) % 11;     // constexpr after unroll
                m0 = fmaf(wk, w01[s].x, m0);
                m1 = fmaf(wk, w01[s].y, m1);
                m2 = fmaf(wk, w23[s].x, m2);
                m3 = fmaf(wk, w23[s].y, m3);
                m4 = fmaf(wk, w4[s],    m4);
            }
            float mu1sq = m0 * m0;
            float mu2sq = m1 * m1;
            float mu12  = m0 * m1;
            float s1sq  = m2 - mu1sq;
            float s2sq  = m3 - mu2sq;
            float s12   = m4 - mu12;
            ssum += ((2.f * mu12 + C1) * (2.f * s12 + C2)) /
                    ((mu1sq + mu2sq + C1) * (s1sq + s2sq + C2));
        }

        // commit pA (plane d+6) into slot j%11 (held plane d-5, now dead)
        {
            const float2 zz = {0.f, 0.f};
            w01[j % 11] = okA ? __half22float2(pA.ab) : zz;
            w23[j % 11] = okA ? __half22float2(pA.cd) : zz;
            w4[j % 11]  = okA ? __half2float(pA4)     : 0.f;
        }
        // shift pipeline and issue plane d+8
        pA = pB; pA4 = pB4; okA = okB;
        {
            int p = d + 8; okB = (p < D_DIM);
            size_t off = (size_t)(okB ? p : 0) * HWN + hw;
            pB = f0123[off]; pB4 = f4[off];
        }
    }

    for (int off = 32; off > 0; off >>= 1)
        ssum += __shfl_down(ssum, off, 64);
    __shared__ float wsum[4];
    int lane = threadIdx.x & 63;
    int wvx  = threadIdx.x >> 6;
    if (lane == 0) wsum[wvx] = ssum;
    __syncthreads();
    if (threadIdx.x == 0) {
        float bs = wsum[0] + wsum[1] + wsum[2] + wsum[3];
        atomicAdd(accum, (double)bs);
    }
}

__global__ void ssim_finalize(const double* __restrict__ accum,
                              float* __restrict__ out)
{
    out[0] = (float)(accum[0] / (double)NTOT);
}

extern "C" void kernel_launch(void* const* d_in, const int* in_sizes, int n_in,
                              void* d_out, int out_size, void* d_ws, size_t ws_size,
                              hipStream_t stream)
{
    const float* img1 = (const float*)d_in[0];
    const float* img2 = (const float*)d_in[1];
    float* out = (float*)d_out;

    GaussW gwts;
    {
        double raw[11], sum = 0.0;
        for (int i = 0; i < 11; ++i) {
            double x = (double)i - 5.0;
            raw[i] = exp(-(x * x) / (2.0 * 1.5 * 1.5));
            sum += raw[i];
        }
        for (int i = 0; i < 11; ++i) gwts.g[i] = (float)(raw[i] / sum);
    }

    // workspace: f0123 (H4[NTOT], 8B) | f4 (half[NTOT], 2B) | accum (8B)
    H4*     f0123 = (H4*)d_ws;
    __half* f4    = (__half*)((char*)d_ws + 8 * NTOT);
    double* accum = (double*)((char*)d_ws + 10 * NTOT);  // 10*NTOT % 8 == 0

    ssim_pass1<<<NWAVES, 64, 0, stream>>>(img1, img2, f0123, f4, accum, gwts);

    dim3 g2(HWN / 256, DCHUNKS); // (144, 4) = 576 blocks
    ssim_pass2<<<g2, 256, 0, stream>>>(f0123, f4, accum, gwts);

    ssim_finalize<<<1, 1, 0, stream>>>(accum, out);
}

// Round 23
// 59.210 us; speedup vs baseline: 1.0750x; 1.0750x over previous
//
#include <hip/hip_runtime.h>
#include <hip/hip_fp16.h>
#include <math.h>

#define D_DIM 160
#define H_DIM 192
#define W_DIM 192
#define HWN   (H_DIM * W_DIM)                 // 36864
#define NTOT  ((size_t)D_DIM * H_DIM * W_DIM) // 5898240

#define C1 0.0001f   // 0.01^2
#define C2 0.0009f   // 0.03^2

#define HSEG 24                    // output rows per wave (measured optimum)
#define NHSEG (H_DIM / HSEG)       // 8
#define NWAVES (NHSEG * 3 * D_DIM) // 3840 (one wave per block)
#define MARCH (HSEG + 10)          // 34 input rows per wave

#define DC 40                      // pass2 d-outputs per block
#define DCHUNKS 4                  // 4*40 = 160 exactly

struct GaussW { float g[11]; };

struct alignas(8) H4 { __half2 ab; __half2 cd; };   // f0,f1 | f2,f3

__device__ __forceinline__ int clampi(int v, int lo, int hi) {
    return min(max(v, lo), hi);
}

// Pass 1 (R21 verbatim — measured best, 59.4 us total): HSEG 24, 1-wave
// blocks, emission-form H-blur, double-buffered LDS row, one fence/step,
// depth-4 global prefetch, fp16 packed output (8B + 2B).
template<int J>
__device__ __forceinline__ void p1_steps(
    const float* __restrict__ pa1, const float* __restrict__ pa2,
    const float* __restrict__ pb1, const float* __restrict__ pb2,
    H4* __restrict__ ep0123, __half* __restrict__ ep4,
    float2* __restrict__ sbuf0, float2* __restrict__ sbuf1,
    const int lane, const bool va, const bool vb,
    const int hbase, const GaussW& gw, float (&rows)[5][11],
    float2 wAv, float2 wAu, float2 wBv, float2 wBu,
    float2 wCv, float2 wCu)
{
    if constexpr (J < MARCH) {
        // issue prefetch for row J+4 (in flight across ~4 steps)
        float2 pfv = {0.f, 0.f}, pfu = {0.f, 0.f};
        if constexpr (J + 4 < MARCH) {
            const int hc = clampi(hbase - 5 + J + 4, 0, H_DIM - 1);
            const size_t ro = (size_t)hc * W_DIM;
            pfv.x = pa1[ro]; pfv.y = pa2[ro];
            pfu.x = pb1[ro]; pfu.y = pb2[ro];
        }

        __builtin_amdgcn_wave_barrier();    // one fence per step

        // stage row J+1 into the other buffer (masked to zero outside)
        if constexpr (J + 1 < MARCH) {
            const int h1 = hbase - 5 + (J + 1);
            const bool ok1 = (h1 >= 0) && (h1 < H_DIM);   // wave-uniform
            float2* wb = ((J + 1) & 1) ? sbuf1 : sbuf0;
            const float2 zz = {0.f, 0.f};
            wb[lane] = (ok1 && va) ? wAv : zz;
            if (lane < 10) wb[64 + lane] = (ok1 && vb) ? wAu : zz;
        }

        // read row J (staged last step; write->read spans a full step);
        // invalid rows record exact zeros (fma(g,0,s)==s bitwise).
        const int hin = hbase - 5 + J;
        float a0 = 0.f, a1 = 0.f, a2 = 0.f, a3 = 0.f, a4 = 0.f;
        if (hin >= 0 && hin < H_DIM) {      // wave-uniform
            const float2* rb = (J & 1) ? sbuf1 : sbuf0;
#pragma unroll
            for (int k = 0; k < 11; ++k) {
                float2 p = rb[lane + k];
                float t1 = gw.g[k] * p.x;
                float t2 = gw.g[k] * p.y;
                a0 += t1;
                a1 += t2;
                a2 = fmaf(t1, p.x, a2);
                a3 = fmaf(t2, p.y, a3);
                a4 = fmaf(t1, p.y, a4);
            }
        }
        rows[0][J % 11] = a0;
        rows[1][J % 11] = a1;
        rows[2][J % 11] = a2;
        rows[3][J % 11] = a3;
        rows[4][J % 11] = a4;

        // output row o = J-10 complete: emission dot-product over the ring
        if constexpr (J >= 10) {
            constexpr int o = J - 10;
            float s0 = 0.f, s1 = 0.f, s2 = 0.f, s3 = 0.f, s4 = 0.f;
#pragma unroll
            for (int k = 0; k < 11; ++k) {
                const float wgt = gw.g[k];
                const int slot = (o + k) % 11;  // constexpr after unroll
                s0 = fmaf(wgt, rows[0][slot], s0);
                s1 = fmaf(wgt, rows[1][slot], s1);
                s2 = fmaf(wgt, rows[2][slot], s2);
                s3 = fmaf(wgt, rows[3][slot], s3);
                s4 = fmaf(wgt, rows[4][slot], s4);
            }
            const size_t rb_ = (size_t)o * W_DIM;
            float2 v01; v01.x = s0; v01.y = s1;
            float2 v23; v23.x = s2; v23.y = s3;
            H4 q;
            q.ab = __float22half2_rn(v01);
            q.cd = __float22half2_rn(v23);
            ep0123[rb_] = q;
            ep4[rb_]    = __float2half_rn(s4);
        }

        p1_steps<J + 1>(pa1, pa2, pb1, pb2, ep0123, ep4, sbuf0, sbuf1,
                        lane, va, vb, hbase, gw, rows,
                        wBv, wBu, wCv, wCu, pfv, pfu);
    }
}

__global__ __launch_bounds__(64) void ssim_pass1(
    const float* __restrict__ img1, const float* __restrict__ img2,
    H4* __restrict__ f0123, __half* __restrict__ f4,
    double* __restrict__ accum, GaussW gw)
{
    // zero reduction cell for pass2 (stream-ordered visibility)
    if (blockIdx.x == 0 && threadIdx.x == 0) accum[0] = 0.0;

    __shared__ float2 sxy[2][80];

    const int lane = threadIdx.x;           // 64-thread block = one wave
    const int wid  = blockIdx.x;
    const int hseg = wid % NHSEG;
    const int t    = wid / NHSEG;
    const int wtile = t % 3;
    const int d     = t / 3;
    const int w0    = wtile * 64;
    const int hbase = hseg * HSEG;

    const int  cola = w0 - 5 + lane;                 // stage col 1
    const bool va   = (cola >= 0) && (cola < W_DIM);
    const int  colb = w0 + 59 + lane;                // stage col 2 (lane<10)
    const bool vb   = (lane < 10) && (colb < W_DIM);
    const int  colac = clampi(cola, 0, W_DIM - 1);   // clamped (masked lanes)
    const int  colbc = min(colb, W_DIM - 1);

    const size_t plane = (size_t)d * HWN;
    const float* pa1 = img1 + plane + colac;
    const float* pa2 = img2 + plane + colac;
    const float* pb1 = img1 + plane + colbc;
    const float* pb2 = img2 + plane + colbc;

    float rows[5][11];
#pragma unroll
    for (int f = 0; f < 5; ++f)
#pragma unroll
        for (int s = 0; s < 11; ++s) rows[f][s] = 0.f;

    float2* sbuf0 = sxy[0];
    float2* sbuf1 = sxy[1];

    // prologue: load rows 0..3; stage row 0 into buf[0]
    float2 r0v, r0u, r1v, r1u, r2v, r2u, r3v, r3u;
    {
        const int h0 = clampi(hbase - 5, 0, H_DIM - 1);
        const int h1 = clampi(hbase - 4, 0, H_DIM - 1);
        const int h2 = clampi(hbase - 3, 0, H_DIM - 1);
        const int h3 = clampi(hbase - 2, 0, H_DIM - 1);
        const size_t q0 = (size_t)h0 * W_DIM;
        const size_t q1 = (size_t)h1 * W_DIM;
        const size_t q2 = (size_t)h2 * W_DIM;
        const size_t q3 = (size_t)h3 * W_DIM;
        r0v.x = pa1[q0]; r0v.y = pa2[q0]; r0u.x = pb1[q0]; r0u.y = pb2[q0];
        r1v.x = pa1[q1]; r1v.y = pa2[q1]; r1u.x = pb1[q1]; r1u.y = pb2[q1];
        r2v.x = pa1[q2]; r2v.y = pa2[q2]; r2u.x = pb1[q2]; r2u.y = pb2[q2];
        r3v.x = pa1[q3]; r3v.y = pa2[q3]; r3u.x = pb1[q3]; r3u.y = pb2[q3];
    }
    {
        const bool ok0 = (hbase - 5 >= 0);           // wave-uniform
        const float2 zz = {0.f, 0.f};
        sbuf0[lane] = (ok0 && va) ? r0v : zz;
        if (lane < 10) sbuf0[64 + lane] = (ok0 && vb) ? r0u : zz;
    }

    const size_t ebase = plane + (size_t)hbase * W_DIM + (w0 + lane);
    H4*     ep0123 = f0123 + ebase;
    __half* ep4    = f4    + ebase;

    p1_steps<0>(pa1, pa2, pb1, pb2, ep0123, ep4, sbuf0, sbuf1,
                lane, va, vb, hbase, gw, rows,
                r1v, r1u, r2v, r2u, r3v, r3u);
}

// Pass 2: R14/R18/R19/R21 VERBATIM (fire-and-forget atomic; absmax 0.0).
__global__ __launch_bounds__(256) void ssim_pass2(
    const H4* __restrict__ f0123, const __half* __restrict__ f4,
    double* __restrict__ accum, GaussW gwts)
{
    const int hw = blockIdx.x * 256 + threadIdx.x;
    const int d0 = blockIdx.y * DC;

    float2 w01[11], w23[11];
    float  w4[11];

    // prologue: planes d0-5 .. d0+5 into slots 0..10 (33 independent loads)
#pragma unroll
    for (int i = 0; i < 11; ++i) {
        int p = d0 - 5 + i;
        bool ok = (p >= 0) && (p < D_DIM);
        size_t off = (size_t)(ok ? p : 0) * HWN + hw;
        float2 zz = {0.f, 0.f};
        H4 q = f0123[off];
        w01[i] = ok ? __half22float2(q.ab) : zz;
        w23[i] = ok ? __half22float2(q.cd) : zz;
        w4[i]  = ok ? __half2float(f4[off]) : 0.f;
    }

    // pending planes d0+6 (pA) and d0+7 (pB), raw fp16 registers
    H4 pA, pB; __half pA4, pB4; bool okA, okB;
    {
        int p = d0 + 6; okA = (p < D_DIM);
        size_t off = (size_t)(okA ? p : 0) * HWN + hw;
        pA = f0123[off]; pA4 = f4[off];
    }
    {
        int p = d0 + 7; okB = (p < D_DIM);
        size_t off = (size_t)(okB ? p : 0) * HWN + hw;
        pB = f0123[off]; pB4 = f4[off];
    }

    float ssum = 0.f;
#pragma unroll
    for (int j = 0; j < DC; ++j) {
        const int d = d0 + j;

        // consume window: planes d-5..d+5 at slots (j+k)%11
        if (d < D_DIM) {
            float m0 = 0.f, m1 = 0.f, m2 = 0.f, m3 = 0.f, m4 = 0.f;
#pragma unroll
            for (int k = 0; k < 11; ++k) {
                const float wk = gwts.g[k];
                const int s = (j + k) % 11;     // constexpr after unroll
                m0 = fmaf(wk, w01[s].x, m0);
                m1 = fmaf(wk, w01[s].y, m1);
                m2 = fmaf(wk, w23[s].x, m2);
                m3 = fmaf(wk, w23[s].y, m3);
                m4 = fmaf(wk, w4[s],    m4);
            }
            float mu1sq = m0 * m0;
            float mu2sq = m1 * m1;
            float mu12  = m0 * m1;
            float s1sq  = m2 - mu1sq;
            float s2sq  = m3 - mu2sq;
            float s12   = m4 - mu12;
            ssum += ((2.f * mu12 + C1) * (2.f * s12 + C2)) /
                    ((mu1sq + mu2sq + C1) * (s1sq + s2sq + C2));
        }

        // commit pA (plane d+6) into slot j%11 (held plane d-5, now dead)
        {
            const float2 zz = {0.f, 0.f};
            w01[j % 11] = okA ? __half22float2(pA.ab) : zz;
            w23[j % 11] = okA ? __half22float2(pA.cd) : zz;
            w4[j % 11]  = okA ? __half2float(pA4)     : 0.f;
        }
        // shift pipeline and issue plane d+8
        pA = pB; pA4 = pB4; okA = okB;
        {
            int p = d + 8; okB = (p < D_DIM);
            size_t off = (size_t)(okB ? p : 0) * HWN + hw;
            pB = f0123[off]; pB4 = f4[off];
        }
    }

    for (int off = 32; off > 0; off >>= 1)
        ssum += __shfl_down(ssum, off, 64);
    __shared__ float wsum[4];
    int lane = threadIdx.x & 63;
    int wvx  = threadIdx.x >> 6;
    if (lane == 0) wsum[wvx] = ssum;
    __syncthreads();
    if (threadIdx.x == 0) {
        float bs = wsum[0] + wsum[1] + wsum[2] + wsum[3];
        atomicAdd(accum, (double)bs);
    }
}

__global__ void ssim_finalize(const double* __restrict__ accum,
                              float* __restrict__ out)
{
    out[0] = (float)(accum[0] / (double)NTOT);
}

extern "C" void kernel_launch(void* const* d_in, const int* in_sizes, int n_in,
                              void* d_out, int out_size, void* d_ws, size_t ws_size,
                              hipStream_t stream)
{
    const float* img1 = (const float*)d_in[0];
    const float* img2 = (const float*)d_in[1];
    float* out = (float*)d_out;

    GaussW gwts;
    {
        double raw[11], sum = 0.0;
        for (int i = 0; i < 11; ++i) {
            double x = (double)i - 5.0;
            raw[i] = exp(-(x * x) / (2.0 * 1.5 * 1.5));
            sum += raw[i];
        }
        for (int i = 0; i < 11; ++i) gwts.g[i] = (float)(raw[i] / sum);
    }

    // workspace: f0123 (H4[NTOT], 8B) | f4 (half[NTOT], 2B) | accum (8B)
    H4*     f0123 = (H4*)d_ws;
    __half* f4    = (__half*)((char*)d_ws + 8 * NTOT);
    double* accum = (double*)((char*)d_ws + 10 * NTOT);  // 10*NTOT % 8 == 0

    ssim_pass1<<<NWAVES, 64, 0, stream>>>(img1, img2, f0123, f4, accum, gwts);

    dim3 g2(HWN / 256, DCHUNKS); // (144, 4) = 576 blocks
    ssim_pass2<<<g2, 256, 0, stream>>>(f0123, f4, accum, gwts);

    ssim_finalize<<<1, 1, 0, stream>>>(accum, out);
}